// Round 4
// baseline (1813.894 us; speedup 1.0000x reference)
//
#include <hip/hip_runtime.h>
#include <hip/hip_bf16.h>

typedef unsigned short u16;
typedef unsigned int u32;

#define SCALE 0.125f

__device__ __forceinline__ float bf2f(u16 u){
    union { u32 i; float f; } c; c.i = ((u32)u) << 16; return c.f;
}
__device__ __forceinline__ u16 f2bf(float f){
    __hip_bfloat16 h = __float2bfloat16(f);
    union { __hip_bfloat16 h; u16 u; } c; c.h = h; return c.u;
}

// ---------------- x = atom_emb[atoms] (fp32 -> fp32) ----------------
__global__ void k_gather(const int* __restrict__ atoms, const float* __restrict__ emb,
                         float* __restrict__ x, int n){
    int i = blockIdx.x * blockDim.x + threadIdx.x;
    if (i >= n * 16) return;
    int node = i >> 4, f = i & 15;
    int a = atoms[node];
    ((float4*)x)[i] = ((const float4*)emb)[a * 16 + f];
}

// ---------------- EW[dh][eid][64] = edge_emb[eid] @ We[dh] ----------------
__global__ void k_ew(const float* __restrict__ edge_emb, const float* __restrict__ We,
                     float* __restrict__ EW){
    int t = blockIdx.x * blockDim.x + threadIdx.x;
    if (t >= 2 * 4 * 3 * 64) return;
    int j = t & 63, r = t >> 6;
    int eid = r % 3, dh = r / 3;
    float s = 0.f;
    for (int c = 0; c < 12; ++c)
        s += edge_emb[eid * 12 + c] * We[(dh * 12 + c) * 64 + j];
    EW[(dh * 3 + eid) * 64 + j] = s;
}

// ---------------- CSR build ----------------
__global__ void k_count(const int* __restrict__ ei, u32* cnt_t, u32* cnt_s, int E){
    int e = blockIdx.x * blockDim.x + threadIdx.x;
    if (e >= E) return;
    atomicAdd(&cnt_t[ei[E + e]], 1u);
    atomicAdd(&cnt_s[ei[e]], 1u);
}

__global__ void k_scan(const u32* __restrict__ cnt_t, const u32* __restrict__ cnt_s,
                       u32* __restrict__ start_t, u32* __restrict__ start_s,
                       u32* totals, int n){
    int i = blockIdx.x * blockDim.x + threadIdx.x;
    int lane = threadIdx.x & 63;
    u32 ct = (i < n) ? cnt_t[i] : 0u;
    u32 cs = (i < n) ? cnt_s[i] : 0u;
    u32 it = ct, is = cs;
    for (int d = 1; d < 64; d <<= 1){
        u32 a = __shfl_up(it, d);
        u32 b = __shfl_up(is, d);
        if (lane >= d){ it += a; is += b; }
    }
    u32 bt = 0, bs = 0;
    if (lane == 63){ bt = atomicAdd(&totals[0], it); bs = atomicAdd(&totals[1], is); }
    bt = __shfl(bt, 63); bs = __shfl(bs, 63);
    if (i < n){ start_t[i] = bt + it - ct; start_s[i] = bs + is - cs; }
}

__global__ void k_fill(const int* __restrict__ ei, const int* __restrict__ eids,
                       const u32* __restrict__ start_t, const u32* __restrict__ start_s,
                       u32* cur_t, u32* cur_s, int* adj_t, int* adj_s, int E){
    int e = blockIdx.x * blockDim.x + threadIdx.x;
    if (e >= E) return;
    int s = ei[e], t = ei[E + e], id = eids[e];
    u32 p = atomicAdd(&cur_t[t], 1u);
    adj_t[start_t[t] + p] = s | (id << 20);
    u32 p2 = atomicAdd(&cur_s[s], 1u);
    adj_s[start_s[s] + p2] = t | (id << 20);
}

// ---------------- fused node GEMM: q,k,v,skip = x @ {Wq,Wk,Wv,Ws} + b ----------------
// q fp32, k/v bf16, skip -> outd fp32. 64-row tile per block, 4x4 register tile/thread.
// Weights converted fp32->bf16 while staging into LDS (error ~2^-9 rel, under threshold).
__global__ __launch_bounds__(256) void k_gemm4(
    const float* __restrict__ x,
    const float* __restrict__ Wq, const float* __restrict__ bq,
    const float* __restrict__ Wk, const float* __restrict__ bk,
    const float* __restrict__ Wv, const float* __restrict__ bv,
    const float* __restrict__ Ws, const float* __restrict__ bs,
    int dh,
    float* __restrict__ q, u16* __restrict__ k, u16* __restrict__ v,
    float* __restrict__ outd, int n)
{
    __shared__ u16 Wl[4][64][64];     // 32 KB (bf16 weights)
    __shared__ float xT[64][64];      // 16 KB, transposed x tile [k][r]
    const int tid = threadIdx.x;

    const float* wsrc[4] = { Wq + dh * 4096, Wk + dh * 4096, Wv + dh * 4096, Ws + dh * 4096 };
    for (int m = 0; m < 4; ++m){
        const float4* src = (const float4*)wsrc[m];
        ushort4* dst = (ushort4*)&Wl[m][0][0];
        for (int i = tid; i < 1024; i += 256){
            float4 w = src[i];
            ushort4 o = { f2bf(w.x), f2bf(w.y), f2bf(w.z), f2bf(w.w) };
            dst[i] = o;
        }
    }

    const int tx = tid & 15, ty = tid >> 4;
    const int c0 = tx * 4, r0 = ty * 4;
    const float* bsrc[4] = { bq + dh * 64, bk + dh * 64, bv + dh * 64, bs + dh * 64 };
    float bias[4][4];
    #pragma unroll
    for (int m = 0; m < 4; ++m)
        #pragma unroll
        for (int j = 0; j < 4; ++j) bias[m][j] = bsrc[m][c0 + j];

    const int row0 = blockIdx.x * 64;
    for (int i = tid; i < 1024; i += 256){   // 64 rows x 16 float4
        int r = i & 63, f = i >> 6;
        int gr = row0 + r;
        float4 val = {0.f, 0.f, 0.f, 0.f};
        if (gr < n) val = ((const float4*)x)[gr * 16 + f];
        xT[f * 4 + 0][r] = val.x; xT[f * 4 + 1][r] = val.y;
        xT[f * 4 + 2][r] = val.z; xT[f * 4 + 3][r] = val.w;
    }
    __syncthreads();

    float acc[4][4][4];
    #pragma unroll
    for (int m = 0; m < 4; ++m)
        #pragma unroll
        for (int i2 = 0; i2 < 4; ++i2)
            #pragma unroll
            for (int j = 0; j < 4; ++j) acc[m][i2][j] = bias[m][j];

    #pragma unroll 4
    for (int kk = 0; kk < 64; ++kk){
        float4 xv = *(const float4*)&xT[kk][r0];
        float xr[4] = { xv.x, xv.y, xv.z, xv.w };
        #pragma unroll
        for (int m = 0; m < 4; ++m){
            ushort4 wu = *(const ushort4*)&Wl[m][kk][c0];
            float wf[4] = { bf2f(wu.x), bf2f(wu.y), bf2f(wu.z), bf2f(wu.w) };
            #pragma unroll
            for (int i2 = 0; i2 < 4; ++i2)
                #pragma unroll
                for (int j = 0; j < 4; ++j)
                    acc[m][i2][j] += xr[i2] * wf[j];
        }
    }

    #pragma unroll
    for (int i2 = 0; i2 < 4; ++i2){
        int gr = row0 + r0 + i2;
        if (gr >= n) continue;
        float4 oq = { acc[0][i2][0], acc[0][i2][1], acc[0][i2][2], acc[0][i2][3] };
        ((float4*)q)[gr * 16 + tx] = oq;
        ushort4 ok = { f2bf(acc[1][i2][0]), f2bf(acc[1][i2][1]), f2bf(acc[1][i2][2]), f2bf(acc[1][i2][3]) };
        ((ushort4*)k)[gr * 16 + tx] = ok;
        ushort4 ov = { f2bf(acc[2][i2][0]), f2bf(acc[2][i2][1]), f2bf(acc[2][i2][2]), f2bf(acc[2][i2][3]) };
        ((ushort4*)v)[gr * 16 + tx] = ov;
        float4 os = { acc[3][i2][0], acc[3][i2][1], acc[3][i2][2], acc[3][i2][3] };
        ((float4*)outd)[gr * 16 + tx] = os;
    }
}

// ---------------- node-parallel attention aggregation (16 lanes per node) ----------------
__global__ __launch_bounds__(256) void k_attn(
    const float* __restrict__ q, const u16* __restrict__ k, const u16* __restrict__ v,
    const int* __restrict__ adj, const u32* __restrict__ start, const u32* __restrict__ cnt,
    const float* __restrict__ EW, float* __restrict__ outd, int n)
{
    int tid = blockIdx.x * blockDim.x + threadIdx.x;
    int node = tid >> 4;
    int l = tid & 15;
    if (node >= n) return;
    int st = (int)start[node];
    int c  = (int)cnt[node];
    float4 q4 = ((const float4*)q)[node * 16 + l];
    float4 acc = {0.f, 0.f, 0.f, 0.f};
    float s = 0.f;
    for (int i = 0; i < c; ++i){
        int a = adj[st + i];
        int srcn = a & 0xFFFFF;
        int eid  = ((u32)a) >> 20;
        float4 ew = ((const float4*)EW)[eid * 16 + l];
        ushort4 ku = ((const ushort4*)k)[srcn * 16 + l];
        float kx = bf2f(ku.x) + ew.x, ky = bf2f(ku.y) + ew.y;
        float kz = bf2f(ku.z) + ew.z, kw = bf2f(ku.w) + ew.w;
        float d = q4.x * kx + q4.y * ky + q4.z * kz + q4.w * kw;
        d += __shfl_xor(d, 1); d += __shfl_xor(d, 2);
        d += __shfl_xor(d, 4); d += __shfl_xor(d, 8);
        float ex = expf(d * SCALE);
        ushort4 vu = ((const ushort4*)v)[srcn * 16 + l];
        acc.x += ex * (bf2f(vu.x) + ew.x);
        acc.y += ex * (bf2f(vu.y) + ew.y);
        acc.z += ex * (bf2f(vu.z) + ew.z);
        acc.w += ex * (bf2f(vu.w) + ew.w);
        s += ex;
    }
    float inv = 1.0f / (s + 1e-16f);
    float4 o = ((float4*)outd)[node * 16 + l];
    o.x += acc.x * inv; o.y += acc.y * inv; o.z += acc.z * inv; o.w += acc.w * inv;
    ((float4*)outd)[node * 16 + l] = o;
}

// ---------------- aggr: x = gelu(concat(o0,o1) @ A + b), fp32 out ----------------
__global__ __launch_bounds__(256) void k_aggr(
    const float* __restrict__ o0, const float* __restrict__ o1,
    const float* __restrict__ A, const float* __restrict__ b,
    float* __restrict__ x, float* __restrict__ out_f, int write_out, int n)
{
    __shared__ u16 Al[128][64];       // 16 KB (bf16 weights)
    __shared__ float t0[64][64];      // 16 KB
    __shared__ float t1[64][64];      // 16 KB
    const int tid = threadIdx.x;
    {
        const float4* src = (const float4*)A;
        ushort4* dst = (ushort4*)&Al[0][0];
        for (int i = tid; i < 2048; i += 256){
            float4 w = src[i];
            ushort4 o = { f2bf(w.x), f2bf(w.y), f2bf(w.z), f2bf(w.w) };
            dst[i] = o;
        }
    }
    const int tx = tid & 15, ty = tid >> 4;
    const int c0 = tx * 4, r0 = ty * 4;
    float bias[4];
    #pragma unroll
    for (int j = 0; j < 4; ++j) bias[j] = b[c0 + j];

    const int row0 = blockIdx.x * 64;
    for (int i = tid; i < 1024; i += 256){
        int r = i & 63, f = i >> 6;
        int gr = row0 + r;
        float4 a = {0.f,0.f,0.f,0.f}, c = {0.f,0.f,0.f,0.f};
        if (gr < n){ a = ((const float4*)o0)[gr * 16 + f]; c = ((const float4*)o1)[gr * 16 + f]; }
        t0[f*4+0][r] = a.x; t0[f*4+1][r] = a.y; t0[f*4+2][r] = a.z; t0[f*4+3][r] = a.w;
        t1[f*4+0][r] = c.x; t1[f*4+1][r] = c.y; t1[f*4+2][r] = c.z; t1[f*4+3][r] = c.w;
    }
    __syncthreads();

    float acc[4][4];
    #pragma unroll
    for (int i2 = 0; i2 < 4; ++i2)
        #pragma unroll
        for (int j = 0; j < 4; ++j) acc[i2][j] = bias[j];

    #pragma unroll 4
    for (int kk = 0; kk < 64; ++kk){
        float4 x0 = *(const float4*)&t0[kk][r0];
        float4 x1 = *(const float4*)&t1[kk][r0];
        ushort4 w0u = *(const ushort4*)&Al[kk][c0];
        ushort4 w1u = *(const ushort4*)&Al[64 + kk][c0];
        float xr0[4] = { x0.x, x0.y, x0.z, x0.w };
        float xr1[4] = { x1.x, x1.y, x1.z, x1.w };
        float w0[4] = { bf2f(w0u.x), bf2f(w0u.y), bf2f(w0u.z), bf2f(w0u.w) };
        float w1[4] = { bf2f(w1u.x), bf2f(w1u.y), bf2f(w1u.z), bf2f(w1u.w) };
        #pragma unroll
        for (int i2 = 0; i2 < 4; ++i2)
            #pragma unroll
            for (int j = 0; j < 4; ++j)
                acc[i2][j] += xr0[i2] * w0[j] + xr1[i2] * w1[j];
    }

    #pragma unroll
    for (int i2 = 0; i2 < 4; ++i2){
        int gr = row0 + r0 + i2;
        if (gr >= n) continue;
        float g[4];
        #pragma unroll
        for (int j = 0; j < 4; ++j){
            float h = acc[i2][j];
            g[j] = 0.5f * h * (1.0f + erff(h * 0.70710678118654752f));
        }
        float4 og = { g[0], g[1], g[2], g[3] };
        ((float4*)x)[gr * 16 + tx] = og;
        if (write_out){
            ((float4*)out_f)[gr * 16 + tx] = og;
        }
    }
}

extern "C" void kernel_launch(void* const* d_in, const int* in_sizes, int n_in,
                              void* d_out, int out_size, void* d_ws, size_t ws_size,
                              hipStream_t stream)
{
    const int* atoms      = (const int*)d_in[0];
    const int* ei         = (const int*)d_in[1];
    const int* eids       = (const int*)d_in[2];
    const float* atom_emb = (const float*)d_in[3];
    const float* edge_emb = (const float*)d_in[4];
    const float* Wq = (const float*)d_in[5];  const float* bq = (const float*)d_in[6];
    const float* Wk = (const float*)d_in[7];  const float* bk = (const float*)d_in[8];
    const float* Wv = (const float*)d_in[9];  const float* bv = (const float*)d_in[10];
    const float* We = (const float*)d_in[11];
    const float* Ws = (const float*)d_in[12]; const float* bs = (const float*)d_in[13];
    const float* aggr_W = (const float*)d_in[14];
    const float* aggr_b = (const float*)d_in[15];

    const int N = in_sizes[0];
    const int E = in_sizes[1] / 2;

    char* p = (char*)d_ws;
    auto alloc = [&](size_t bytes){
        void* r = (void*)p;
        p += (bytes + 255) & ~(size_t)255;
        return r;
    };
    float* x   = (float*)alloc((size_t)N * 64 * 4);
    float* q   = (float*)alloc((size_t)N * 64 * 4);
    u16*   kb  = (u16*)  alloc((size_t)N * 64 * 2);
    u16*   vb  = (u16*)  alloc((size_t)N * 64 * 2);
    float* o0  = (float*)alloc((size_t)N * 64 * 4);
    float* o1  = (float*)alloc((size_t)N * 64 * 4);
    float* EWt = (float*)alloc(2 * 4 * 3 * 64 * 4);
    int* adj_t = (int*)alloc((size_t)E * 4);
    int* adj_s = (int*)alloc((size_t)E * 4);
    u32* start_t = (u32*)alloc((size_t)N * 4);
    u32* start_s = (u32*)alloc((size_t)N * 4);
    u32* zb = (u32*)alloc(((size_t)4 * N + 2) * 4);   // cnt_t cnt_s cur_t cur_s totals
    u32* cnt_t = zb;
    u32* cnt_s = zb + N;
    u32* cur_t = zb + 2 * (size_t)N;
    u32* cur_s = zb + 3 * (size_t)N;
    u32* totals = zb + 4 * (size_t)N;

    hipMemsetAsync(zb, 0, ((size_t)4 * N + 2) * 4, stream);

    k_gather<<<(N * 16 + 255) / 256, 256, 0, stream>>>(atoms, atom_emb, x, N);
    k_ew<<<6, 256, 0, stream>>>(edge_emb, We, EWt);
    k_count<<<(E + 255) / 256, 256, 0, stream>>>(ei, cnt_t, cnt_s, E);
    k_scan<<<(N + 255) / 256, 256, 0, stream>>>(cnt_t, cnt_s, start_t, start_s, totals, N);
    k_fill<<<(E + 255) / 256, 256, 0, stream>>>(ei, eids, start_t, start_s, cur_t, cur_s, adj_t, adj_s, E);

    const int gB = (N + 63) / 64;
    const int gA = (N * 16 + 255) / 256;
    for (int hop = 0; hop < 4; ++hop){
        int dh0 = hop;         // dir 0 (r2c)
        int dh1 = 4 + hop;     // dir 1 (c2r)
        k_gemm4<<<gB, 256, 0, stream>>>(x, Wq, bq, Wk, bk, Wv, bv, Ws, bs, dh0, q, kb, vb, o0, N);
        k_attn<<<gA, 256, 0, stream>>>(q, kb, vb, adj_t, start_t, cnt_t, EWt + dh0 * 192, o0, N);
        k_gemm4<<<gB, 256, 0, stream>>>(x, Wq, bq, Wk, bk, Wv, bv, Ws, bs, dh1, q, kb, vb, o1, N);
        k_attn<<<gA, 256, 0, stream>>>(q, kb, vb, adj_s, start_s, cnt_s, EWt + dh1 * 192, o1, N);
        k_aggr<<<gB, 256, 0, stream>>>(o0, o1, aggr_W, aggr_b, x, (float*)d_out, hop == 3 ? 1 : 0, N);
    }
}

// Round 6
// 1446.999 us; speedup vs baseline: 1.2536x; 1.2536x over previous
//
#include <hip/hip_runtime.h>
#include <hip/hip_bf16.h>

typedef unsigned short u16;
typedef unsigned int u32;
typedef __attribute__((ext_vector_type(8))) short short8v;
typedef __attribute__((ext_vector_type(4))) float f32x4;

#define SCALE 0.125f

__device__ __forceinline__ float bf2f(u16 u){
    union { u32 i; float f; } c; c.i = ((u32)u) << 16; return c.f;
}
__device__ __forceinline__ u16 f2bf(float f){
    __hip_bfloat16 h = __float2bfloat16(f);
    union { __hip_bfloat16 h; u16 u; } c; c.h = h; return c.u;
}

// ---------------- x = atom_emb[atoms] (fp32 -> fp32) ----------------
__global__ void k_gather(const int* __restrict__ atoms, const float* __restrict__ emb,
                         float* __restrict__ x, int n){
    int i = blockIdx.x * blockDim.x + threadIdx.x;
    if (i >= n * 16) return;
    int node = i >> 4, f = i & 15;
    int a = atoms[node];
    ((float4*)x)[i] = ((const float4*)emb)[a * 16 + f];
}

// ---------------- EW[dh][eid][64] = edge_emb[eid] @ We[dh] ----------------
__global__ void k_ew(const float* __restrict__ edge_emb, const float* __restrict__ We,
                     float* __restrict__ EW){
    int t = blockIdx.x * blockDim.x + threadIdx.x;
    if (t >= 2 * 4 * 3 * 64) return;
    int j = t & 63, r = t >> 6;
    int eid = r % 3, dh = r / 3;
    float s = 0.f;
    for (int c = 0; c < 12; ++c)
        s += edge_emb[eid * 12 + c] * We[(dh * 12 + c) * 64 + j];
    EW[(dh * 3 + eid) * 64 + j] = s;
}

// ---------------- CSR build ----------------
__global__ void k_count(const int* __restrict__ ei, u32* cnt_t, u32* cnt_s, int E){
    int e = blockIdx.x * blockDim.x + threadIdx.x;
    if (e >= E) return;
    atomicAdd(&cnt_t[ei[E + e]], 1u);
    atomicAdd(&cnt_s[ei[e]], 1u);
}

__global__ void k_scan(const u32* __restrict__ cnt_t, const u32* __restrict__ cnt_s,
                       u32* __restrict__ start_t, u32* __restrict__ start_s,
                       u32* totals, int n){
    int i = blockIdx.x * blockDim.x + threadIdx.x;
    int lane = threadIdx.x & 63;
    u32 ct = (i < n) ? cnt_t[i] : 0u;
    u32 cs = (i < n) ? cnt_s[i] : 0u;
    u32 it = ct, is = cs;
    for (int d = 1; d < 64; d <<= 1){
        u32 a = __shfl_up(it, d);
        u32 b = __shfl_up(is, d);
        if (lane >= d){ it += a; is += b; }
    }
    u32 bt = 0, bs = 0;
    if (lane == 63){ bt = atomicAdd(&totals[0], it); bs = atomicAdd(&totals[1], is); }
    bt = __shfl(bt, 63); bs = __shfl(bs, 63);
    if (i < n){ start_t[i] = bt + it - ct; start_s[i] = bs + is - cs; }
}

__global__ void k_fill(const int* __restrict__ ei, const int* __restrict__ eids,
                       const u32* __restrict__ start_t, const u32* __restrict__ start_s,
                       u32* cur_t, u32* cur_s, int* adj_t, int* adj_s, int E){
    int e = blockIdx.x * blockDim.x + threadIdx.x;
    if (e >= E) return;
    int s = ei[e], t = ei[E + e], id = eids[e];
    u32 p = atomicAdd(&cur_t[t], 1u);
    adj_t[start_t[t] + p] = s | (id << 20);
    u32 p2 = atomicAdd(&cur_s[s], 1u);
    adj_s[start_s[s] + p2] = t | (id << 20);
}

// ---------------- fused node GEMM via MFMA: q,k,v,skip = x @ {Wq,Wk,Wv,Ws} + b ----
// 64-row tile/block, 4 waves, each wave: 16 rows x 64 cols x 4 mats.
// x split hi/lo bf16 (2 MFMAs) => precision == fp32-x X bf16-W (same as prev round).
// LDS XOR-swizzle: 16B slot ^= (row&7) so stride-128B fragment reads spread banks.
__global__ __launch_bounds__(256) void k_gemm4(
    const float* __restrict__ x,
    const float* __restrict__ Wq, const float* __restrict__ bq,
    const float* __restrict__ Wk, const float* __restrict__ bk,
    const float* __restrict__ Wv, const float* __restrict__ bv,
    const float* __restrict__ Ws, const float* __restrict__ bs,
    int dh,
    u16* __restrict__ q, u16* __restrict__ k, u16* __restrict__ v,
    float* __restrict__ outd, int n)
{
    __shared__ __align__(16) u16 Wt[4][64][64];   // [mat][n][k] bf16, swizzled, 32 KB
    __shared__ __align__(16) u16 Xh[64][64];      // x hi, [r][k] swizzled, 8 KB
    __shared__ __align__(16) u16 Xl[64][64];      // x lo residual, 8 KB
    const int tid = threadIdx.x;
    const int row0 = blockIdx.x * 64;

    // ---- stage weights transposed W[k][n] -> Wt[n][k] (bf16, swizzled) ----
    const float* wsrc[4] = { Wq + dh * 4096, Wk + dh * 4096, Wv + dh * 4096, Ws + dh * 4096 };
    for (int m = 0; m < 4; ++m){
        for (int i = tid; i < 1024; i += 256){    // 64 k-rows x 16 float4
            int kk = i >> 4, n4 = (i & 15) * 4;
            float4 w = ((const float4*)(wsrc[m] + (size_t)kk * 64))[i & 15];
            float wf[4] = { w.x, w.y, w.z, w.w };
            #pragma unroll
            for (int c = 0; c < 4; ++c){
                int nn = n4 + c;
                int ps = (kk >> 3) ^ (nn & 7);
                Wt[m][nn][ps * 8 + (kk & 7)] = f2bf(wf[c]);
            }
        }
    }
    // ---- stage x hi/lo (swizzled) ----
    for (int i = tid; i < 1024; i += 256){        // 64 rows x 16 float4
        int r = i >> 4, f = i & 15;
        int gr = row0 + r;
        float4 val = {0.f,0.f,0.f,0.f};
        if (gr < n) val = ((const float4*)x)[(size_t)gr * 16 + f];
        float fv[4] = { val.x, val.y, val.z, val.w };
        int ps = (f >> 1) ^ (r & 7);
        int base = ps * 8 + (f & 1) * 4;
        #pragma unroll
        for (int c = 0; c < 4; ++c){
            u16 hb = f2bf(fv[c]);
            Xh[r][base + c] = hb;
            Xl[r][base + c] = f2bf(fv[c] - bf2f(hb));
        }
    }
    __syncthreads();

    const int wv = tid >> 6, l = tid & 63;
    const int lr = l & 15, lk = l >> 4;           // A: row lr (+16*wv), k-base lk*8
    // ---- A fragments (2 k-steps, hi+lo) ----
    short8v ah[2], al[2];
    #pragma unroll
    for (int ks = 0; ks < 2; ++ks){
        int r = wv * 16 + lr;
        int ps = (lk + 4 * ks) ^ (r & 7);
        ah[ks] = *(const short8v*)&Xh[r][ps * 8];
        al[ks] = *(const short8v*)&Xl[r][ps * 8];
    }
    const float* bsrc[4] = { bq + dh * 64, bk + dh * 64, bv + dh * 64, bs + dh * 64 };
    u16* outs[3] = { q, k, v };
    for (int m = 0; m < 4; ++m){
        #pragma unroll
        for (int ct = 0; ct < 4; ++ct){
            int col = ct * 16 + lr;
            int s0 = (lk + 0) ^ (col & 7);
            int s1 = (lk + 4) ^ (col & 7);
            short8v b0 = *(const short8v*)&Wt[m][col][s0 * 8];
            short8v b1 = *(const short8v*)&Wt[m][col][s1 * 8];
            float bb = bsrc[m][col];
            f32x4 acc = { bb, bb, bb, bb };
            acc = __builtin_amdgcn_mfma_f32_16x16x32_bf16(ah[0], b0, acc, 0, 0, 0);
            acc = __builtin_amdgcn_mfma_f32_16x16x32_bf16(al[0], b0, acc, 0, 0, 0);
            acc = __builtin_amdgcn_mfma_f32_16x16x32_bf16(ah[1], b1, acc, 0, 0, 0);
            acc = __builtin_amdgcn_mfma_f32_16x16x32_bf16(al[1], b1, acc, 0, 0, 0);
            int grb = row0 + wv * 16 + lk * 4;    // D: row = (l>>4)*4+j, col = l&15 (m89)
            if (m < 3){
                u16* o = outs[m];
                #pragma unroll
                for (int j = 0; j < 4; ++j)
                    if (grb + j < n) o[(size_t)(grb + j) * 64 + col] = f2bf(acc[j]);
            } else {
                #pragma unroll
                for (int j = 0; j < 4; ++j)
                    if (grb + j < n) outd[(size_t)(grb + j) * 64 + col] = acc[j];
            }
        }
    }
}

// ---------------- node-parallel attention aggregation (16 lanes per node) ----------------
__global__ __launch_bounds__(256) void k_attn(
    const u16* __restrict__ q, const u16* __restrict__ k, const u16* __restrict__ v,
    const int* __restrict__ adj, const u32* __restrict__ start, const u32* __restrict__ cnt,
    const float* __restrict__ EW, float* __restrict__ outd, int n)
{
    int tid = blockIdx.x * blockDim.x + threadIdx.x;
    int node = tid >> 4;
    int l = tid & 15;
    if (node >= n) return;
    int st = (int)start[node];
    int c  = (int)cnt[node];
    ushort4 qu = ((const ushort4*)q)[node * 16 + l];
    float qx = bf2f(qu.x), qy = bf2f(qu.y), qz = bf2f(qu.z), qw = bf2f(qu.w);
    float4 acc = {0.f, 0.f, 0.f, 0.f};
    float s = 0.f;
    for (int i = 0; i < c; ++i){
        int a = adj[st + i];
        int srcn = a & 0xFFFFF;
        int eid  = ((u32)a) >> 20;
        float4 ew = ((const float4*)EW)[eid * 16 + l];
        ushort4 ku = ((const ushort4*)k)[srcn * 16 + l];
        float kx = bf2f(ku.x) + ew.x, ky = bf2f(ku.y) + ew.y;
        float kz = bf2f(ku.z) + ew.z, kw = bf2f(ku.w) + ew.w;
        float d = qx * kx + qy * ky + qz * kz + qw * kw;
        d += __shfl_xor(d, 1); d += __shfl_xor(d, 2);
        d += __shfl_xor(d, 4); d += __shfl_xor(d, 8);
        float ex = expf(d * SCALE);
        ushort4 vu = ((const ushort4*)v)[srcn * 16 + l];
        acc.x += ex * (bf2f(vu.x) + ew.x);
        acc.y += ex * (bf2f(vu.y) + ew.y);
        acc.z += ex * (bf2f(vu.z) + ew.z);
        acc.w += ex * (bf2f(vu.w) + ew.w);
        s += ex;
    }
    float inv = 1.0f / (s + 1e-16f);
    float4 o = ((float4*)outd)[node * 16 + l];
    o.x += acc.x * inv; o.y += acc.y * inv; o.z += acc.z * inv; o.w += acc.w * inv;
    ((float4*)outd)[node * 16 + l] = o;
}

// ---------------- aggr via MFMA: x = gelu(concat(o0,o1) @ A + b) ----------------
__global__ __launch_bounds__(256) void k_aggr(
    const float* __restrict__ o0, const float* __restrict__ o1,
    const float* __restrict__ A, const float* __restrict__ b,
    float* __restrict__ x, float* __restrict__ out_f, int write_out, int n)
{
    __shared__ __align__(16) u16 Wt[64][128];   // [n][k] bf16 swizzled, 16 KB
    __shared__ __align__(16) u16 Ah[64][128];   // concat(o0,o1) hi, 16 KB
    __shared__ __align__(16) u16 Al_[64][128];  // lo residual, 16 KB
    const int tid = threadIdx.x;
    const int row0 = blockIdx.x * 64;

    // ---- stage W^T: A_w[k][n] (128x64) -> Wt[n][k] ----
    for (int i = tid; i < 2048; i += 256){       // 128 k-rows x 16 float4
        int kk = i >> 4, n4 = (i & 15) * 4;
        float4 w = ((const float4*)(A + (size_t)kk * 64))[i & 15];
        float wf[4] = { w.x, w.y, w.z, w.w };
        #pragma unroll
        for (int c = 0; c < 4; ++c){
            int nn = n4 + c;
            int ps = (kk >> 3) ^ (nn & 7);       // 16 slots/row; xor low 3 bits
            Wt[nn][ps * 8 + (kk & 7)] = f2bf(wf[c]);
        }
    }
    // ---- stage A rows hi/lo: k<64 from o0, k>=64 from o1 ----
    for (int i = tid; i < 2048; i += 256){       // 64 rows x 32 float4
        int r = i >> 5, f = i & 31;
        int gr = row0 + r;
        float4 val = {0.f,0.f,0.f,0.f};
        if (gr < n){
            if (f < 16) val = ((const float4*)o0)[(size_t)gr * 16 + f];
            else        val = ((const float4*)o1)[(size_t)gr * 16 + (f - 16)];
        }
        float fv[4] = { val.x, val.y, val.z, val.w };
        int ps = (f >> 1) ^ (r & 7);
        int base = ps * 8 + (f & 1) * 4;
        #pragma unroll
        for (int c = 0; c < 4; ++c){
            u16 hb = f2bf(fv[c]);
            Ah[r][base + c] = hb;
            Al_[r][base + c] = f2bf(fv[c] - bf2f(hb));
        }
    }
    __syncthreads();

    const int wv = tid >> 6, l = tid & 63;
    const int lr = l & 15, lk = l >> 4;
    short8v ah[4], al[4];
    #pragma unroll
    for (int ks = 0; ks < 4; ++ks){
        int r = wv * 16 + lr;
        int ps = (lk + 4 * ks) ^ (r & 7);
        ah[ks] = *(const short8v*)&Ah[r][ps * 8];
        al[ks] = *(const short8v*)&Al_[r][ps * 8];
    }
    #pragma unroll
    for (int ct = 0; ct < 4; ++ct){
        int col = ct * 16 + lr;
        float bb = b[col];
        f32x4 acc = { bb, bb, bb, bb };
        #pragma unroll
        for (int ks = 0; ks < 4; ++ks){
            int ps = (lk + 4 * ks) ^ (col & 7);
            short8v bf = *(const short8v*)&Wt[col][ps * 8];
            acc = __builtin_amdgcn_mfma_f32_16x16x32_bf16(ah[ks], bf, acc, 0, 0, 0);
            acc = __builtin_amdgcn_mfma_f32_16x16x32_bf16(al[ks], bf, acc, 0, 0, 0);
        }
        int grb = row0 + wv * 16 + lk * 4;
        #pragma unroll
        for (int j = 0; j < 4; ++j){
            if (grb + j >= n) continue;
            float h = acc[j];
            float g = 0.5f * h * (1.0f + erff(h * 0.70710678118654752f));
            x[(size_t)(grb + j) * 64 + col] = g;
            if (write_out) out_f[(size_t)(grb + j) * 64 + col] = g;
        }
    }
}

extern "C" void kernel_launch(void* const* d_in, const int* in_sizes, int n_in,
                              void* d_out, int out_size, void* d_ws, size_t ws_size,
                              hipStream_t stream)
{
    const int* atoms      = (const int*)d_in[0];
    const int* ei         = (const int*)d_in[1];
    const int* eids       = (const int*)d_in[2];
    const float* atom_emb = (const float*)d_in[3];
    const float* edge_emb = (const float*)d_in[4];
    const float* Wq = (const float*)d_in[5];  const float* bq = (const float*)d_in[6];
    const float* Wk = (const float*)d_in[7];  const float* bk = (const float*)d_in[8];
    const float* Wv = (const float*)d_in[9];  const float* bv = (const float*)d_in[10];
    const float* We = (const float*)d_in[11];
    const float* Ws = (const float*)d_in[12]; const float* bs = (const float*)d_in[13];
    const float* aggr_W = (const float*)d_in[14];
    const float* aggr_b = (const float*)d_in[15];

    const int N = in_sizes[0];
    const int E = in_sizes[1] / 2;

    char* p = (char*)d_ws;
    auto alloc = [&](size_t bytes){
        void* r = (void*)p;
        p += (bytes + 255) & ~(size_t)255;
        return r;
    };
    float* x   = (float*)alloc((size_t)N * 64 * 4);
    u16*   qb  = (u16*)  alloc((size_t)N * 64 * 2);
    u16*   kb  = (u16*)  alloc((size_t)N * 64 * 2);
    u16*   vb  = (u16*)  alloc((size_t)N * 64 * 2);
    float* o0  = (float*)alloc((size_t)N * 64 * 4);
    float* o1  = (float*)alloc((size_t)N * 64 * 4);
    float* EWt = (float*)alloc(2 * 4 * 3 * 64 * 4);
    int* adj_t = (int*)alloc((size_t)E * 4);
    int* adj_s = (int*)alloc((size_t)E * 4);
    u32* start_t = (u32*)alloc((size_t)N * 4);
    u32* start_s = (u32*)alloc((size_t)N * 4);
    u32* zb = (u32*)alloc(((size_t)4 * N + 2) * 4);   // cnt_t cnt_s cur_t cur_s totals
    u32* cnt_t = zb;
    u32* cnt_s = zb + N;
    u32* cur_t = zb + 2 * (size_t)N;
    u32* cur_s = zb + 3 * (size_t)N;
    u32* totals = zb + 4 * (size_t)N;

    hipMemsetAsync(zb, 0, ((size_t)4 * N + 2) * 4, stream);

    k_gather<<<(N * 16 + 255) / 256, 256, 0, stream>>>(atoms, atom_emb, x, N);
    k_ew<<<6, 256, 0, stream>>>(edge_emb, We, EWt);
    k_count<<<(E + 255) / 256, 256, 0, stream>>>(ei, cnt_t, cnt_s, E);
    k_scan<<<(N + 255) / 256, 256, 0, stream>>>(cnt_t, cnt_s, start_t, start_s, totals, N);
    k_fill<<<(E + 255) / 256, 256, 0, stream>>>(ei, eids, start_t, start_s, cur_t, cur_s, adj_t, adj_s, E);

    const int gB = (N + 63) / 64;
    const int gA = (N * 16 + 255) / 256;
    for (int hop = 0; hop < 4; ++hop){
        int dh0 = hop;         // dir 0 (r2c)
        int dh1 = 4 + hop;     // dir 1 (c2r)
        k_gemm4<<<gB, 256, 0, stream>>>(x, Wq, bq, Wk, bk, Wv, bv, Ws, bs, dh0, qb, kb, vb, o0, N);
        k_attn<<<gA, 256, 0, stream>>>(qb, kb, vb, adj_t, start_t, cnt_t, EWt + dh0 * 192, o0, N);
        k_gemm4<<<gB, 256, 0, stream>>>(x, Wq, bq, Wk, bk, Wv, bv, Ws, bs, dh1, qb, kb, vb, o1, N);
        k_attn<<<gA, 256, 0, stream>>>(qb, kb, vb, adj_s, start_s, cnt_s, EWt + dh1 * 192, o1, N);
        k_aggr<<<gB, 256, 0, stream>>>(o0, o1, aggr_W, aggr_b, x, (float*)d_out, hop == 3 ? 1 : 0, N);
    }
}

// Round 8
// 1381.761 us; speedup vs baseline: 1.3127x; 1.0472x over previous
//
#include <hip/hip_runtime.h>
#include <hip/hip_bf16.h>

typedef unsigned short u16;
typedef unsigned int u32;
typedef unsigned long long u64;
typedef __attribute__((ext_vector_type(8))) short short8v;
typedef __attribute__((ext_vector_type(4))) float f32x4;

#define SCALE 0.125f

__device__ __forceinline__ float bf2f(u16 u){
    union { u32 i; float f; } c; c.i = ((u32)u) << 16; return c.f;
}
__device__ __forceinline__ u16 f2bf(float f){
    __hip_bfloat16 h = __float2bfloat16(f);
    union { __hip_bfloat16 h; u16 u; } c; c.h = h; return c.u;
}

// ---------------- x = atom_emb[atoms] (fp32 -> fp32) ----------------
__global__ void k_gather(const int* __restrict__ atoms, const float* __restrict__ emb,
                         float* __restrict__ x, int n){
    int i = blockIdx.x * blockDim.x + threadIdx.x;
    if (i >= n * 16) return;
    int node = i >> 4, f = i & 15;
    int a = atoms[node];
    ((float4*)x)[i] = ((const float4*)emb)[a * 16 + f];
}

// ---------------- EW[dh][eid][64] = edge_emb[eid] @ We[dh] ----------------
__global__ void k_ew(const float* __restrict__ edge_emb, const float* __restrict__ We,
                     float* __restrict__ EW){
    int t = blockIdx.x * blockDim.x + threadIdx.x;
    if (t >= 2 * 4 * 3 * 64) return;
    int j = t & 63, r = t >> 6;
    int eid = r % 3, dh = r / 3;
    float s = 0.f;
    for (int c = 0; c < 12; ++c)
        s += edge_emb[eid * 12 + c] * We[(dh * 12 + c) * 64 + j];
    EW[(dh * 3 + eid) * 64 + j] = s;
}

// ---------------- CSR build ----------------
__global__ void k_count(const int* __restrict__ ei, u32* cnt_t, u32* cnt_s, int E){
    int e = blockIdx.x * blockDim.x + threadIdx.x;
    if (e >= E) return;
    atomicAdd(&cnt_t[ei[E + e]], 1u);
    atomicAdd(&cnt_s[ei[e]], 1u);
}

// Hierarchical scan: 1024 elems/block (4/thread), wave shfl scan, LDS wave partials,
// ONE packed u64 atomic per block (t low 32, s high 32; totals <= E < 2^32 so no carry).
__global__ __launch_bounds__(256) void k_scan(
    const u32* __restrict__ cnt_t, const u32* __restrict__ cnt_s,
    u32* __restrict__ start_t, u32* __restrict__ start_s,
    u64* __restrict__ totals, int n)
{
    __shared__ u32 wsum_t[4], wsum_s[4];
    __shared__ u32 base_t, base_s;
    const int t0 = blockIdx.x * 1024 + threadIdx.x * 4;
    u32 ct[4], cs[4];
    #pragma unroll
    for (int j = 0; j < 4; ++j){
        int idx = t0 + j;
        ct[j] = (idx < n) ? cnt_t[idx] : 0u;
        cs[j] = (idx < n) ? cnt_s[idx] : 0u;
    }
    u32 tsum_t = ct[0] + ct[1] + ct[2] + ct[3];
    u32 tsum_s = cs[0] + cs[1] + cs[2] + cs[3];
    const int lane = threadIdx.x & 63, wv = threadIdx.x >> 6;
    u32 it = tsum_t, is = tsum_s;
    for (int d = 1; d < 64; d <<= 1){
        u32 a = __shfl_up(it, d);
        u32 b = __shfl_up(is, d);
        if (lane >= d){ it += a; is += b; }
    }
    if (lane == 63){ wsum_t[wv] = it; wsum_s[wv] = is; }
    __syncthreads();
    if (threadIdx.x == 0){
        u32 a0 = wsum_t[0], a1 = wsum_t[1], a2 = wsum_t[2], a3 = wsum_t[3];
        u32 b0 = wsum_s[0], b1 = wsum_s[1], b2 = wsum_s[2], b3 = wsum_s[3];
        u64 old = atomicAdd(totals, ((u64)(b0 + b1 + b2 + b3) << 32) | (u64)(a0 + a1 + a2 + a3));
        base_t = (u32)(old & 0xFFFFFFFFull);
        base_s = (u32)(old >> 32);
        wsum_t[0] = 0; wsum_t[1] = a0; wsum_t[2] = a0 + a1; wsum_t[3] = a0 + a1 + a2;
        wsum_s[0] = 0; wsum_s[1] = b0; wsum_s[2] = b0 + b1; wsum_s[3] = b0 + b1 + b2;
    }
    __syncthreads();
    u32 ex_t = base_t + wsum_t[wv] + (it - tsum_t);
    u32 ex_s = base_s + wsum_s[wv] + (is - tsum_s);
    #pragma unroll
    for (int j = 0; j < 4; ++j){
        int idx = t0 + j;
        if (idx < n){
            start_t[idx] = ex_t; start_s[idx] = ex_s;
            ex_t += ct[j]; ex_s += cs[j];
        }
    }
}

__global__ void k_fill(const int* __restrict__ ei, const int* __restrict__ eids,
                       const u32* __restrict__ start_t, const u32* __restrict__ start_s,
                       u32* cur_t, u32* cur_s, int* adj_t, int* adj_s, int E){
    int e = blockIdx.x * blockDim.x + threadIdx.x;
    if (e >= E) return;
    int s = ei[e], t = ei[E + e], id = eids[e];
    u32 p = atomicAdd(&cur_t[t], 1u);
    adj_t[start_t[t] + p] = s | (id << 20);
    u32 p2 = atomicAdd(&cur_s[s], 1u);
    adj_s[start_s[s] + p2] = t | (id << 20);
}

// ---------------- fused node GEMM via MFMA: q,k,v,skip = x @ {Wq,Wk,Wv,Ws} + b ----
// 64-row tile/block, 4 waves, each wave: 16 rows x 64 cols x 4 mats.
// x split hi/lo bf16 (2 MFMAs) => precision == fp32-x X bf16-W.
// LDS XOR-swizzle: 16B slot ^= (row&7) so stride-128B fragment reads spread banks.
__global__ __launch_bounds__(256) void k_gemm4(
    const float* __restrict__ x,
    const float* __restrict__ Wq, const float* __restrict__ bq,
    const float* __restrict__ Wk, const float* __restrict__ bk,
    const float* __restrict__ Wv, const float* __restrict__ bv,
    const float* __restrict__ Ws, const float* __restrict__ bs,
    int dh,
    u16* __restrict__ q, u16* __restrict__ k, u16* __restrict__ v,
    float* __restrict__ outd, int n)
{
    __shared__ __align__(16) u16 Wt[4][64][64];   // [mat][n][k] bf16, swizzled, 32 KB
    __shared__ __align__(16) u16 Xh[64][64];      // x hi, [r][k] swizzled, 8 KB
    __shared__ __align__(16) u16 Xl[64][64];      // x lo residual, 8 KB
    const int tid = threadIdx.x;
    const int row0 = blockIdx.x * 64;

    const float* wsrc[4] = { Wq + dh * 4096, Wk + dh * 4096, Wv + dh * 4096, Ws + dh * 4096 };
    for (int m = 0; m < 4; ++m){
        for (int i = tid; i < 1024; i += 256){    // 64 k-rows x 16 float4
            int kk = i >> 4, n4 = (i & 15) * 4;
            float4 w = ((const float4*)(wsrc[m] + (size_t)kk * 64))[i & 15];
            float wf[4] = { w.x, w.y, w.z, w.w };
            #pragma unroll
            for (int c = 0; c < 4; ++c){
                int nn = n4 + c;
                int ps = (kk >> 3) ^ (nn & 7);
                Wt[m][nn][ps * 8 + (kk & 7)] = f2bf(wf[c]);
            }
        }
    }
    for (int i = tid; i < 1024; i += 256){        // 64 rows x 16 float4
        int r = i >> 4, f = i & 15;
        int gr = row0 + r;
        float4 val = {0.f,0.f,0.f,0.f};
        if (gr < n) val = ((const float4*)x)[(size_t)gr * 16 + f];
        float fv[4] = { val.x, val.y, val.z, val.w };
        int ps = (f >> 1) ^ (r & 7);
        int base = ps * 8 + (f & 1) * 4;
        #pragma unroll
        for (int c = 0; c < 4; ++c){
            u16 hb = f2bf(fv[c]);
            Xh[r][base + c] = hb;
            Xl[r][base + c] = f2bf(fv[c] - bf2f(hb));
        }
    }
    __syncthreads();

    const int wv = tid >> 6, l = tid & 63;
    const int lr = l & 15, lk = l >> 4;
    short8v ah[2], al[2];
    #pragma unroll
    for (int ks = 0; ks < 2; ++ks){
        int r = wv * 16 + lr;
        int ps = (lk + 4 * ks) ^ (r & 7);
        ah[ks] = *(const short8v*)&Xh[r][ps * 8];
        al[ks] = *(const short8v*)&Xl[r][ps * 8];
    }
    const float* bsrc[4] = { bq + dh * 64, bk + dh * 64, bv + dh * 64, bs + dh * 64 };
    u16* outs[3] = { q, k, v };
    for (int m = 0; m < 4; ++m){
        #pragma unroll
        for (int ct = 0; ct < 4; ++ct){
            int col = ct * 16 + lr;
            int s0 = (lk + 0) ^ (col & 7);
            int s1 = (lk + 4) ^ (col & 7);
            short8v b0 = *(const short8v*)&Wt[m][col][s0 * 8];
            short8v b1 = *(const short8v*)&Wt[m][col][s1 * 8];
            float bb = bsrc[m][col];
            f32x4 acc = { bb, bb, bb, bb };
            acc = __builtin_amdgcn_mfma_f32_16x16x32_bf16(ah[0], b0, acc, 0, 0, 0);
            acc = __builtin_amdgcn_mfma_f32_16x16x32_bf16(al[0], b0, acc, 0, 0, 0);
            acc = __builtin_amdgcn_mfma_f32_16x16x32_bf16(ah[1], b1, acc, 0, 0, 0);
            acc = __builtin_amdgcn_mfma_f32_16x16x32_bf16(al[1], b1, acc, 0, 0, 0);
            int grb = row0 + wv * 16 + lk * 4;
            if (m < 3){
                u16* o = outs[m];
                #pragma unroll
                for (int j = 0; j < 4; ++j)
                    if (grb + j < n) o[(size_t)(grb + j) * 64 + col] = f2bf(acc[j]);
            } else {
                #pragma unroll
                for (int j = 0; j < 4; ++j)
                    if (grb + j < n) outd[(size_t)(grb + j) * 64 + col] = acc[j];
            }
        }
    }
}

// ---------------- node-parallel attention aggregation (16 lanes per node) ----------------
__global__ __launch_bounds__(256) void k_attn(
    const u16* __restrict__ q, const u16* __restrict__ k, const u16* __restrict__ v,
    const int* __restrict__ adj, const u32* __restrict__ start, const u32* __restrict__ cnt,
    const float* __restrict__ EW, float* __restrict__ outd, int n)
{
    int tid = blockIdx.x * blockDim.x + threadIdx.x;
    int node = tid >> 4;
    int l = tid & 15;
    if (node >= n) return;
    int st = (int)start[node];
    int c  = (int)cnt[node];
    ushort4 qu = ((const ushort4*)q)[node * 16 + l];
    float qx = bf2f(qu.x), qy = bf2f(qu.y), qz = bf2f(qu.z), qw = bf2f(qu.w);
    float4 acc = {0.f, 0.f, 0.f, 0.f};
    float s = 0.f;
    for (int i = 0; i < c; ++i){
        int a = adj[st + i];
        int srcn = a & 0xFFFFF;
        int eid  = ((u32)a) >> 20;
        float4 ew = ((const float4*)EW)[eid * 16 + l];
        ushort4 ku = ((const ushort4*)k)[srcn * 16 + l];
        float kx = bf2f(ku.x) + ew.x, ky = bf2f(ku.y) + ew.y;
        float kz = bf2f(ku.z) + ew.z, kw = bf2f(ku.w) + ew.w;
        float d = qx * kx + qy * ky + qz * kz + qw * kw;
        d += __shfl_xor(d, 1); d += __shfl_xor(d, 2);
        d += __shfl_xor(d, 4); d += __shfl_xor(d, 8);
        float ex = expf(d * SCALE);
        ushort4 vu = ((const ushort4*)v)[srcn * 16 + l];
        acc.x += ex * (bf2f(vu.x) + ew.x);
        acc.y += ex * (bf2f(vu.y) + ew.y);
        acc.z += ex * (bf2f(vu.z) + ew.z);
        acc.w += ex * (bf2f(vu.w) + ew.w);
        s += ex;
    }
    float inv = 1.0f / (s + 1e-16f);
    float4 o = ((float4*)outd)[node * 16 + l];
    o.x += acc.x * inv; o.y += acc.y * inv; o.z += acc.z * inv; o.w += acc.w * inv;
    ((float4*)outd)[node * 16 + l] = o;
}

// ---------------- aggr via MFMA: x = gelu(concat(o0,o1) @ A + b) ----------------
__global__ __launch_bounds__(256) void k_aggr(
    const float* __restrict__ o0, const float* __restrict__ o1,
    const float* __restrict__ A, const float* __restrict__ b,
    float* __restrict__ x, float* __restrict__ out_f, int write_out, int n)
{
    __shared__ __align__(16) u16 Wt[64][128];   // [n][k] bf16 swizzled, 16 KB
    __shared__ __align__(16) u16 Ah[64][128];   // concat(o0,o1) hi, 16 KB
    __shared__ __align__(16) u16 Al_[64][128];  // lo residual, 16 KB
    const int tid = threadIdx.x;
    const int row0 = blockIdx.x * 64;

    for (int i = tid; i < 2048; i += 256){       // 128 k-rows x 16 float4
        int kk = i >> 4, n4 = (i & 15) * 4;
        float4 w = ((const float4*)(A + (size_t)kk * 64))[i & 15];
        float wf[4] = { w.x, w.y, w.z, w.w };
        #pragma unroll
        for (int c = 0; c < 4; ++c){
            int nn = n4 + c;
            int ps = (kk >> 3) ^ (nn & 7);
            Wt[nn][ps * 8 + (kk & 7)] = f2bf(wf[c]);
        }
    }
    for (int i = tid; i < 2048; i += 256){       // 64 rows x 32 float4
        int r = i >> 5, f = i & 31;
        int gr = row0 + r;
        float4 val = {0.f,0.f,0.f,0.f};
        if (gr < n){
            if (f < 16) val = ((const float4*)o0)[(size_t)gr * 16 + f];
            else        val = ((const float4*)o1)[(size_t)gr * 16 + (f - 16)];
        }
        float fv[4] = { val.x, val.y, val.z, val.w };
        int ps = (f >> 1) ^ (r & 7);
        int base = ps * 8 + (f & 1) * 4;
        #pragma unroll
        for (int c = 0; c < 4; ++c){
            u16 hb = f2bf(fv[c]);
            Ah[r][base + c] = hb;
            Al_[r][base + c] = f2bf(fv[c] - bf2f(hb));
        }
    }
    __syncthreads();

    const int wv = tid >> 6, l = tid & 63;
    const int lr = l & 15, lk = l >> 4;
    short8v ah[4], al[4];
    #pragma unroll
    for (int ks = 0; ks < 4; ++ks){
        int r = wv * 16 + lr;
        int ps = (lk + 4 * ks) ^ (r & 7);
        ah[ks] = *(const short8v*)&Ah[r][ps * 8];
        al[ks] = *(const short8v*)&Al_[r][ps * 8];
    }
    #pragma unroll
    for (int ct = 0; ct < 4; ++ct){
        int col = ct * 16 + lr;
        float bb = b[col];
        f32x4 acc = { bb, bb, bb, bb };
        #pragma unroll
        for (int ks = 0; ks < 4; ++ks){
            int ps = (lk + 4 * ks) ^ (col & 7);
            short8v bf = *(const short8v*)&Wt[col][ps * 8];
            acc = __builtin_amdgcn_mfma_f32_16x16x32_bf16(ah[ks], bf, acc, 0, 0, 0);
            acc = __builtin_amdgcn_mfma_f32_16x16x32_bf16(al[ks], bf, acc, 0, 0, 0);
        }
        int grb = row0 + wv * 16 + lk * 4;
        #pragma unroll
        for (int j = 0; j < 4; ++j){
            if (grb + j >= n) continue;
            float h = acc[j];
            float g = 0.5f * h * (1.0f + erff(h * 0.70710678118654752f));
            x[(size_t)(grb + j) * 64 + col] = g;
            if (write_out) out_f[(size_t)(grb + j) * 64 + col] = g;
        }
    }
}

extern "C" void kernel_launch(void* const* d_in, const int* in_sizes, int n_in,
                              void* d_out, int out_size, void* d_ws, size_t ws_size,
                              hipStream_t stream)
{
    const int* atoms      = (const int*)d_in[0];
    const int* ei         = (const int*)d_in[1];
    const int* eids       = (const int*)d_in[2];
    const float* atom_emb = (const float*)d_in[3];
    const float* edge_emb = (const float*)d_in[4];
    const float* Wq = (const float*)d_in[5];  const float* bq = (const float*)d_in[6];
    const float* Wk = (const float*)d_in[7];  const float* bk = (const float*)d_in[8];
    const float* Wv = (const float*)d_in[9];  const float* bv = (const float*)d_in[10];
    const float* We = (const float*)d_in[11];
    const float* Ws = (const float*)d_in[12]; const float* bs = (const float*)d_in[13];
    const float* aggr_W = (const float*)d_in[14];
    const float* aggr_b = (const float*)d_in[15];

    const int N = in_sizes[0];
    const int E = in_sizes[1] / 2;

    char* p = (char*)d_ws;
    auto alloc = [&](size_t bytes){
        void* r = (void*)p;
        p += (bytes + 255) & ~(size_t)255;
        return r;
    };
    float* x   = (float*)alloc((size_t)N * 64 * 4);
    u16*   qb  = (u16*)  alloc((size_t)N * 64 * 2);
    u16*   kb  = (u16*)  alloc((size_t)N * 64 * 2);
    u16*   vb  = (u16*)  alloc((size_t)N * 64 * 2);
    float* o0  = (float*)alloc((size_t)N * 64 * 4);
    float* o1  = (float*)alloc((size_t)N * 64 * 4);
    float* EWt = (float*)alloc(2 * 4 * 3 * 64 * 4);
    int* adj_t = (int*)alloc((size_t)E * 4);
    int* adj_s = (int*)alloc((size_t)E * 4);
    u32* start_t = (u32*)alloc((size_t)N * 4);
    u32* start_s = (u32*)alloc((size_t)N * 4);
    u32* zb = (u32*)alloc(((size_t)4 * N + 2) * 4);   // cnt_t cnt_s cur_t cur_s totals(u64)
    u32* cnt_t = zb;
    u32* cnt_s = zb + N;
    u32* cur_t = zb + 2 * (size_t)N;
    u32* cur_s = zb + 3 * (size_t)N;
    u64* totals = (u64*)(zb + 4 * (size_t)N);   // 4N u32s = 8-byte aligned

    hipMemsetAsync(zb, 0, ((size_t)4 * N + 2) * 4, stream);

    k_gather<<<(N * 16 + 255) / 256, 256, 0, stream>>>(atoms, atom_emb, x, N);
    k_ew<<<6, 256, 0, stream>>>(edge_emb, We, EWt);
    k_count<<<(E + 255) / 256, 256, 0, stream>>>(ei, cnt_t, cnt_s, E);
    k_scan<<<(N + 1023) / 1024, 256, 0, stream>>>(cnt_t, cnt_s, start_t, start_s, totals, N);
    k_fill<<<(E + 255) / 256, 256, 0, stream>>>(ei, eids, start_t, start_s, cur_t, cur_s, adj_t, adj_s, E);

    const int gB = (N + 63) / 64;
    const int gA = (N * 16 + 255) / 256;
    for (int hop = 0; hop < 4; ++hop){
        int dh0 = hop;         // dir 0 (r2c)
        int dh1 = 4 + hop;     // dir 1 (c2r)
        k_gemm4<<<gB, 256, 0, stream>>>(x, Wq, bq, Wk, bk, Wv, bv, Ws, bs, dh0, qb, kb, vb, o0, N);
        k_attn<<<gA, 256, 0, stream>>>(qb, kb, vb, adj_t, start_t, cnt_t, EWt + dh0 * 192, o0, N);
        k_gemm4<<<gB, 256, 0, stream>>>(x, Wq, bq, Wk, bk, Wv, bv, Ws, bs, dh1, qb, kb, vb, o1, N);
        k_attn<<<gA, 256, 0, stream>>>(qb, kb, vb, adj_s, start_s, cnt_s, EWt + dh1 * 192, o1, N);
        k_aggr<<<gB, 256, 0, stream>>>(o0, o1, aggr_W, aggr_b, x, (float*)d_out, hop == 3 ? 1 : 0, N);
    }
}

// Round 10
// 1121.729 us; speedup vs baseline: 1.6171x; 1.2318x over previous
//
#include <hip/hip_runtime.h>
#include <hip/hip_bf16.h>

typedef unsigned short u16;
typedef unsigned int u32;
typedef unsigned long long u64;
typedef __attribute__((ext_vector_type(8))) short short8v;
typedef __attribute__((ext_vector_type(4))) float f32x4;

#define SCALE 0.125f

__device__ __forceinline__ float bf2f(u16 u){
    union { u32 i; float f; } c; c.i = ((u32)u) << 16; return c.f;
}
__device__ __forceinline__ u16 f2bf(float f){
    __hip_bfloat16 h = __float2bfloat16(f);
    union { __hip_bfloat16 h; u16 u; } c; c.h = h; return c.u;
}

// ---------------- x = atom_emb[atoms] (fp32 -> bf16) ----------------
__global__ void k_gather(const int* __restrict__ atoms, const float* __restrict__ emb,
                         u16* __restrict__ x, int n){
    int i = blockIdx.x * blockDim.x + threadIdx.x;
    if (i >= n * 16) return;
    int node = i >> 4, f = i & 15;
    int a = atoms[node];
    float4 v = ((const float4*)emb)[a * 16 + f];
    ushort4 o = { f2bf(v.x), f2bf(v.y), f2bf(v.z), f2bf(v.w) };
    ((ushort4*)x)[i] = o;
}

// ---------------- EW[dh][eid][64] = edge_emb[eid] @ We[dh] ----------------
__global__ void k_ew(const float* __restrict__ edge_emb, const float* __restrict__ We,
                     float* __restrict__ EW){
    int t = blockIdx.x * blockDim.x + threadIdx.x;
    if (t >= 2 * 4 * 3 * 64) return;
    int j = t & 63, r = t >> 6;
    int eid = r % 3, dh = r / 3;
    float s = 0.f;
    for (int c = 0; c < 12; ++c)
        s += edge_emb[eid * 12 + c] * We[(dh * 12 + c) * 64 + j];
    EW[(dh * 3 + eid) * 64 + j] = s;
}

// ---------------- CSR build ----------------
__global__ void k_count(const int* __restrict__ ei, u32* cnt_t, u32* cnt_s, int E){
    int e = blockIdx.x * blockDim.x + threadIdx.x;
    if (e >= E) return;
    atomicAdd(&cnt_t[ei[E + e]], 1u);
    atomicAdd(&cnt_s[ei[e]], 1u);
}

// Hierarchical scan: 1024 elems/block (4/thread), ONE packed u64 atomic per block.
__global__ __launch_bounds__(256) void k_scan(
    const u32* __restrict__ cnt_t, const u32* __restrict__ cnt_s,
    u32* __restrict__ start_t, u32* __restrict__ start_s,
    u64* __restrict__ totals, int n)
{
    __shared__ u32 wsum_t[4], wsum_s[4];
    __shared__ u32 base_t, base_s;
    const int t0 = blockIdx.x * 1024 + threadIdx.x * 4;
    u32 ct[4], cs[4];
    #pragma unroll
    for (int j = 0; j < 4; ++j){
        int idx = t0 + j;
        ct[j] = (idx < n) ? cnt_t[idx] : 0u;
        cs[j] = (idx < n) ? cnt_s[idx] : 0u;
    }
    u32 tsum_t = ct[0] + ct[1] + ct[2] + ct[3];
    u32 tsum_s = cs[0] + cs[1] + cs[2] + cs[3];
    const int lane = threadIdx.x & 63, wv = threadIdx.x >> 6;
    u32 it = tsum_t, is = tsum_s;
    for (int d = 1; d < 64; d <<= 1){
        u32 a = __shfl_up(it, d);
        u32 b = __shfl_up(is, d);
        if (lane >= d){ it += a; is += b; }
    }
    if (lane == 63){ wsum_t[wv] = it; wsum_s[wv] = is; }
    __syncthreads();
    if (threadIdx.x == 0){
        u32 a0 = wsum_t[0], a1 = wsum_t[1], a2 = wsum_t[2], a3 = wsum_t[3];
        u32 b0 = wsum_s[0], b1 = wsum_s[1], b2 = wsum_s[2], b3 = wsum_s[3];
        u64 old = atomicAdd(totals, ((u64)(b0 + b1 + b2 + b3) << 32) | (u64)(a0 + a1 + a2 + a3));
        base_t = (u32)(old & 0xFFFFFFFFull);
        base_s = (u32)(old >> 32);
        wsum_t[0] = 0; wsum_t[1] = a0; wsum_t[2] = a0 + a1; wsum_t[3] = a0 + a1 + a2;
        wsum_s[0] = 0; wsum_s[1] = b0; wsum_s[2] = b0 + b1; wsum_s[3] = b0 + b1 + b2;
    }
    __syncthreads();
    u32 ex_t = base_t + wsum_t[wv] + (it - tsum_t);
    u32 ex_s = base_s + wsum_s[wv] + (is - tsum_s);
    #pragma unroll
    for (int j = 0; j < 4; ++j){
        int idx = t0 + j;
        if (idx < n){
            start_t[idx] = ex_t; start_s[idx] = ex_s;
            ex_t += ct[j]; ex_s += cs[j];
        }
    }
}

__global__ void k_fill(const int* __restrict__ ei, const int* __restrict__ eids,
                       const u32* __restrict__ start_t, const u32* __restrict__ start_s,
                       u32* cur_t, u32* cur_s, int* adj_t, int* adj_s, int E){
    int e = blockIdx.x * blockDim.x + threadIdx.x;
    if (e >= E) return;
    int s = ei[e], t = ei[E + e], id = eids[e];
    u32 p = atomicAdd(&cur_t[t], 1u);
    adj_t[start_t[t] + p] = s | (id << 20);
    u32 p2 = atomicAdd(&cur_s[s], 1u);
    adj_s[start_s[s] + p2] = t | (id << 20);
}

// ---------------- fused node GEMM via MFMA: q,k,v,skip = x @ {Wq,Wk,Wv,Ws} + b ----
// x is bf16 (exact) -> single A-path. All outputs bf16.
// LDS XOR-swizzle: 16B slot ^= (row&7).
__global__ __launch_bounds__(256) void k_gemm4(
    const u16* __restrict__ x,
    const float* __restrict__ Wq, const float* __restrict__ bq,
    const float* __restrict__ Wk, const float* __restrict__ bk,
    const float* __restrict__ Wv, const float* __restrict__ bv,
    const float* __restrict__ Ws, const float* __restrict__ bs,
    int dh,
    u16* __restrict__ q, u16* __restrict__ k, u16* __restrict__ v,
    u16* __restrict__ outd, int n)
{
    __shared__ __align__(16) u16 Wt[4][64][64];   // [mat][n][k] bf16, swizzled, 32 KB
    __shared__ __align__(16) u16 Xh[64][64];      // x tile, swizzled, 8 KB
    const int tid = threadIdx.x;
    const int row0 = blockIdx.x * 64;

    const float* wsrc[4] = { Wq + dh * 4096, Wk + dh * 4096, Wv + dh * 4096, Ws + dh * 4096 };
    for (int m = 0; m < 4; ++m){
        for (int i = tid; i < 1024; i += 256){    // 64 k-rows x 16 float4
            int kk = i >> 4, n4 = (i & 15) * 4;
            float4 w = ((const float4*)(wsrc[m] + (size_t)kk * 64))[i & 15];
            float wf[4] = { w.x, w.y, w.z, w.w };
            #pragma unroll
            for (int c = 0; c < 4; ++c){
                int nn = n4 + c;
                int ps = (kk >> 3) ^ (nn & 7);
                Wt[m][nn][ps * 8 + (kk & 7)] = f2bf(wf[c]);
            }
        }
    }
    for (int i = tid; i < 512; i += 256){         // 64 rows x 8 slots (16B each)
        int r = i >> 3, f = i & 7;
        int gr = row0 + r;
        short8v val = {0,0,0,0,0,0,0,0};
        if (gr < n) val = *(const short8v*)&x[(size_t)gr * 64 + f * 8];
        int ps = f ^ (r & 7);
        *(short8v*)&Xh[r][ps * 8] = val;
    }
    __syncthreads();

    const int wv = tid >> 6, l = tid & 63;
    const int lr = l & 15, lk = l >> 4;
    short8v ah[2];
    #pragma unroll
    for (int ks = 0; ks < 2; ++ks){
        int r = wv * 16 + lr;
        int ps = (lk + 4 * ks) ^ (r & 7);
        ah[ks] = *(const short8v*)&Xh[r][ps * 8];
    }
    const float* bsrc[4] = { bq + dh * 64, bk + dh * 64, bv + dh * 64, bs + dh * 64 };
    u16* outs[4] = { q, k, v, outd };
    for (int m = 0; m < 4; ++m){
        #pragma unroll
        for (int ct = 0; ct < 4; ++ct){
            int col = ct * 16 + lr;
            int s0 = (lk + 0) ^ (col & 7);
            int s1 = (lk + 4) ^ (col & 7);
            short8v b0 = *(const short8v*)&Wt[m][col][s0 * 8];
            short8v b1 = *(const short8v*)&Wt[m][col][s1 * 8];
            float bb = bsrc[m][col];
            f32x4 acc = { bb, bb, bb, bb };
            acc = __builtin_amdgcn_mfma_f32_16x16x32_bf16(ah[0], b0, acc, 0, 0, 0);
            acc = __builtin_amdgcn_mfma_f32_16x16x32_bf16(ah[1], b1, acc, 0, 0, 0);
            int grb = row0 + wv * 16 + lk * 4;    // D: row=(l>>4)*4+j, col=l&15
            u16* o = outs[m];
            #pragma unroll
            for (int j = 0; j < 4; ++j)
                if (grb + j < n) o[(size_t)(grb + j) * 64 + col] = f2bf(acc[j]);
        }
    }
}

// ---------------- node-parallel attention aggregation (16 lanes per node) ----------------
// outd (skip, bf16) read-modify-write: out = skip + attn.
__global__ __launch_bounds__(256) void k_attn(
    const u16* __restrict__ q, const u16* __restrict__ k, const u16* __restrict__ v,
    const int* __restrict__ adj, const u32* __restrict__ start, const u32* __restrict__ cnt,
    const float* __restrict__ EW, u16* __restrict__ outd, int n)
{
    int tid = blockIdx.x * blockDim.x + threadIdx.x;
    int node = tid >> 4;
    int l = tid & 15;
    if (node >= n) return;
    int st = (int)start[node];
    int c  = (int)cnt[node];
    ushort4 qu = ((const ushort4*)q)[node * 16 + l];
    float qx = bf2f(qu.x), qy = bf2f(qu.y), qz = bf2f(qu.z), qw = bf2f(qu.w);
    float4 acc = {0.f, 0.f, 0.f, 0.f};
    float s = 0.f;
    for (int i = 0; i < c; ++i){
        int a = adj[st + i];
        int srcn = a & 0xFFFFF;
        int eid  = ((u32)a) >> 20;
        float4 ew = ((const float4*)EW)[eid * 16 + l];
        ushort4 ku = ((const ushort4*)k)[srcn * 16 + l];
        float kx = bf2f(ku.x) + ew.x, ky = bf2f(ku.y) + ew.y;
        float kz = bf2f(ku.z) + ew.z, kw = bf2f(ku.w) + ew.w;
        float d = qx * kx + qy * ky + qz * kz + qw * kw;
        d += __shfl_xor(d, 1); d += __shfl_xor(d, 2);
        d += __shfl_xor(d, 4); d += __shfl_xor(d, 8);
        float ex = expf(d * SCALE);
        ushort4 vu = ((const ushort4*)v)[srcn * 16 + l];
        acc.x += ex * (bf2f(vu.x) + ew.x);
        acc.y += ex * (bf2f(vu.y) + ew.y);
        acc.z += ex * (bf2f(vu.z) + ew.z);
        acc.w += ex * (bf2f(vu.w) + ew.w);
        s += ex;
    }
    float inv = 1.0f / (s + 1e-16f);
    ushort4 ou = ((const ushort4*)outd)[node * 16 + l];
    ushort4 no = { f2bf(bf2f(ou.x) + acc.x * inv), f2bf(bf2f(ou.y) + acc.y * inv),
                   f2bf(bf2f(ou.z) + acc.z * inv), f2bf(bf2f(ou.w) + acc.w * inv) };
    ((ushort4*)outd)[node * 16 + l] = no;
}

// ---------------- aggr via MFMA: x = gelu(concat(o0,o1) @ A + b) ----------------
// o0/o1 bf16 in, x bf16 out; final output fp32 from fp32 accumulator.
__global__ __launch_bounds__(256) void k_aggr(
    const u16* __restrict__ o0, const u16* __restrict__ o1,
    const float* __restrict__ A, const float* __restrict__ b,
    u16* __restrict__ x, float* __restrict__ out_f, int write_out, int n)
{
    __shared__ __align__(16) u16 Wt[64][128];   // [n][k] bf16 swizzled, 16 KB
    __shared__ __align__(16) u16 Ah[64][128];   // concat(o0,o1) tile, 16 KB
    const int tid = threadIdx.x;
    const int row0 = blockIdx.x * 64;

    for (int i = tid; i < 2048; i += 256){       // 128 k-rows x 16 float4
        int kk = i >> 4, n4 = (i & 15) * 4;
        float4 w = ((const float4*)(A + (size_t)kk * 64))[i & 15];
        float wf[4] = { w.x, w.y, w.z, w.w };
        #pragma unroll
        for (int c = 0; c < 4; ++c){
            int nn = n4 + c;
            int ps = (kk >> 3) ^ (nn & 7);
            Wt[nn][ps * 8 + (kk & 7)] = f2bf(wf[c]);
        }
    }
    for (int i = tid; i < 1024; i += 256){       // 64 rows x 16 slots (16B each)
        int r = i >> 4, j = i & 15;
        int gr = row0 + r;
        short8v val = {0,0,0,0,0,0,0,0};
        if (gr < n){
            if (j < 8) val = *(const short8v*)&o0[(size_t)gr * 64 + j * 8];
            else       val = *(const short8v*)&o1[(size_t)gr * 64 + (j - 8) * 8];
        }
        int ps = j ^ (r & 7);                     // bit3 of j preserved (xor low 3)
        *(short8v*)&Ah[r][ps * 8] = val;
    }
    __syncthreads();

    const int wv = tid >> 6, l = tid & 63;
    const int lr = l & 15, lk = l >> 4;
    short8v ah[4];
    #pragma unroll
    for (int ks = 0; ks < 4; ++ks){
        int r = wv * 16 + lr;
        int ps = (lk + 4 * ks) ^ (r & 7);
        ah[ks] = *(const short8v*)&Ah[r][ps * 8];
    }
    #pragma unroll
    for (int ct = 0; ct < 4; ++ct){
        int col = ct * 16 + lr;
        float bb = b[col];
        f32x4 acc = { bb, bb, bb, bb };
        #pragma unroll
        for (int ks = 0; ks < 4; ++ks){
            int ps = (lk + 4 * ks) ^ (col & 7);
            short8v bf = *(const short8v*)&Wt[col][ps * 8];
            acc = __builtin_amdgcn_mfma_f32_16x16x32_bf16(ah[ks], bf, acc, 0, 0, 0);
        }
        int grb = row0 + wv * 16 + lk * 4;
        #pragma unroll
        for (int j = 0; j < 4; ++j){
            if (grb + j >= n) continue;
            float h = acc[j];
            float g = 0.5f * h * (1.0f + erff(h * 0.70710678118654752f));
            x[(size_t)(grb + j) * 64 + col] = f2bf(g);
            if (write_out) out_f[(size_t)(grb + j) * 64 + col] = g;
        }
    }
}

extern "C" void kernel_launch(void* const* d_in, const int* in_sizes, int n_in,
                              void* d_out, int out_size, void* d_ws, size_t ws_size,
                              hipStream_t stream)
{
    const int* atoms      = (const int*)d_in[0];
    const int* ei         = (const int*)d_in[1];
    const int* eids       = (const int*)d_in[2];
    const float* atom_emb = (const float*)d_in[3];
    const float* edge_emb = (const float*)d_in[4];
    const float* Wq = (const float*)d_in[5];  const float* bq = (const float*)d_in[6];
    const float* Wk = (const float*)d_in[7];  const float* bk = (const float*)d_in[8];
    const float* Wv = (const float*)d_in[9];  const float* bv = (const float*)d_in[10];
    const float* We = (const float*)d_in[11];
    const float* Ws = (const float*)d_in[12]; const float* bs = (const float*)d_in[13];
    const float* aggr_W = (const float*)d_in[14];
    const float* aggr_b = (const float*)d_in[15];

    const int N = in_sizes[0];
    const int E = in_sizes[1] / 2;

    char* p = (char*)d_ws;
    auto alloc = [&](size_t bytes){
        void* r = (void*)p;
        p += (bytes + 255) & ~(size_t)255;
        return r;
    };
    u16*   x   = (u16*)  alloc((size_t)N * 64 * 2);
    u16*   qb  = (u16*)  alloc((size_t)N * 64 * 2);
    u16*   kb  = (u16*)  alloc((size_t)N * 64 * 2);
    u16*   vb  = (u16*)  alloc((size_t)N * 64 * 2);
    u16*   o0  = (u16*)  alloc((size_t)N * 64 * 2);
    u16*   o1  = (u16*)  alloc((size_t)N * 64 * 2);
    float* EWt = (float*)alloc(2 * 4 * 3 * 64 * 4);
    int* adj_t = (int*)alloc((size_t)E * 4);
    int* adj_s = (int*)alloc((size_t)E * 4);
    u32* start_t = (u32*)alloc((size_t)N * 4);
    u32* start_s = (u32*)alloc((size_t)N * 4);
    u32* zb = (u32*)alloc(((size_t)4 * N + 2) * 4);   // cnt_t cnt_s cur_t cur_s totals(u64)
    u32* cnt_t = zb;
    u32* cnt_s = zb + N;
    u32* cur_t = zb + 2 * (size_t)N;
    u32* cur_s = zb + 3 * (size_t)N;
    u64* totals = (u64*)(zb + 4 * (size_t)N);   // 4N u32s = 8-byte aligned

    hipMemsetAsync(zb, 0, ((size_t)4 * N + 2) * 4, stream);

    k_gather<<<(N * 16 + 255) / 256, 256, 0, stream>>>(atoms, atom_emb, x, N);
    k_ew<<<6, 256, 0, stream>>>(edge_emb, We, EWt);
    k_count<<<(E + 255) / 256, 256, 0, stream>>>(ei, cnt_t, cnt_s, E);
    k_scan<<<(N + 1023) / 1024, 256, 0, stream>>>(cnt_t, cnt_s, start_t, start_s, totals, N);
    k_fill<<<(E + 255) / 256, 256, 0, stream>>>(ei, eids, start_t, start_s, cur_t, cur_s, adj_t, adj_s, E);

    const int gB = (N + 63) / 64;
    const int gA = (N * 16 + 255) / 256;
    for (int hop = 0; hop < 4; ++hop){
        int dh0 = hop;         // dir 0 (r2c)
        int dh1 = 4 + hop;     // dir 1 (c2r)
        k_gemm4<<<gB, 256, 0, stream>>>(x, Wq, bq, Wk, bk, Wv, bv, Ws, bs, dh0, qb, kb, vb, o0, N);
        k_attn<<<gA, 256, 0, stream>>>(qb, kb, vb, adj_t, start_t, cnt_t, EWt + dh0 * 192, o0, N);
        k_gemm4<<<gB, 256, 0, stream>>>(x, Wq, bq, Wk, bk, Wv, bv, Ws, bs, dh1, qb, kb, vb, o1, N);
        k_attn<<<gA, 256, 0, stream>>>(qb, kb, vb, adj_s, start_s, cnt_s, EWt + dh1 * 192, o1, N);
        k_aggr<<<gB, 256, 0, stream>>>(o0, o1, aggr_W, aggr_b, x, (float*)d_out, hop == 3 ? 1 : 0, N);
    }
}